// Round 1
// baseline (3882.570 us; speedup 1.0000x reference)
//
#include <hip/hip_runtime.h>
#include <hip/hip_bf16.h>
#include <math.h>

#define N_NODES 10000
#define N_EDGES 320000
#define CH 64
#define SH_PAD 12   // sh stored padded to 12 floats/row for 16B-aligned stores
#define MIXW 192    // N_L * CH

// ---------- small helpers ----------
__device__ __forceinline__ float bf2f(unsigned short u) {
    union { unsigned int i; float f; } v; v.i = ((unsigned int)u) << 16; return v.f;
}
__device__ __forceinline__ unsigned short f2bf(float f) {
    unsigned int x = __float_as_uint(f);
    unsigned int r = x + 0x7fffu + ((x >> 16) & 1u);   // RNE
    return (unsigned short)(r >> 16);
}
__device__ __forceinline__ float silu(float t) {
    return t / (1.0f + __expf(-t));
}

// ---------- K1: h = (node_feats @ W_up) / 8 ----------
__global__ __launch_bounds__(256) void k_h(const float* __restrict__ nf,
                                           const float* __restrict__ Wup,
                                           float* __restrict__ h) {
    int node = __builtin_amdgcn_readfirstlane(blockIdx.x * 4 + (threadIdx.x >> 6));
    int lane = threadIdx.x & 63;
    const float* nrow = nf + (size_t)node * CH;
    float acc = 0.f;
#pragma unroll
    for (int k = 0; k < CH; ++k) acc += nrow[k] * Wup[k * CH + lane];
    h[(size_t)node * CH + lane] = acc * 0.125f;
}

// ---------- K2: per-edge spherical harmonics + radial MLP ----------
__global__ __launch_bounds__(256) void k_edge(const float* __restrict__ ev,
                                              const float* __restrict__ rad,
                                              const float* __restrict__ W1,
                                              const float* __restrict__ W2,
                                              const float* __restrict__ W3,
                                              const float* __restrict__ W4,
                                              float* __restrict__ shb,
                                              unsigned short* __restrict__ mix) {
    int e = blockIdx.x * 256 + threadIdx.x;

    // --- spherical harmonics (component-normalized, l<=2) ---
    float vx = ev[(size_t)e * 3 + 0], vy = ev[(size_t)e * 3 + 1], vz = ev[(size_t)e * 3 + 2];
    float inv = rsqrtf(vx * vx + vy * vy + vz * vz);
    float x = vx * inv, y = vy * inv, z = vz * inv;
    const float s3 = 1.7320508075688772f;
    const float s15 = 3.872983346207417f;
    const float s5 = 2.2360679774997896f;
    float4* sp = (float4*)(shb + (size_t)e * SH_PAD);
    sp[0] = make_float4(1.0f, s3 * x, s3 * y, s3 * z);
    sp[1] = make_float4(s15 * x * y, s15 * y * z, 0.5f * s5 * (3.0f * z * z - 1.0f), s15 * x * z);
    sp[2] = make_float4(0.5f * s15 * (x * x - y * y), 0.f, 0.f, 0.f);

    // --- radial MLP: 8 -> 64 -> 64 -> 64 -> 192 ---
    const float4* rp = (const float4*)(rad + (size_t)e * 8);
    float4 r01 = rp[0], r23 = rp[1];
    float r[8] = { r01.x, r01.y, r01.z, r01.w, r23.x, r23.y, r23.z, r23.w };

    float a[64], b[64];

    // layer 1: [8] -> [64], scale 1/sqrt(8), silu
#pragma unroll
    for (int j = 0; j < 64; ++j) {
        float t = 0.f;
#pragma unroll
        for (int k = 0; k < 8; ++k) t += r[k] * W1[k * 64 + j];
        a[j] = silu(t * 0.3535533905932738f);
    }

    // layer 2: [64] -> [64], scale 1/8, silu
#pragma unroll
    for (int j0 = 0; j0 < 64; j0 += 8) {
        float acc[8] = {0.f, 0.f, 0.f, 0.f, 0.f, 0.f, 0.f, 0.f};
#pragma unroll
        for (int k = 0; k < 64; ++k) {
            float av = a[k];
#pragma unroll
            for (int jj = 0; jj < 8; ++jj) acc[jj] += av * W2[k * 64 + j0 + jj];
        }
#pragma unroll
        for (int jj = 0; jj < 8; ++jj) b[j0 + jj] = silu(acc[jj] * 0.125f);
    }

    // layer 3: [64] -> [64], scale 1/8, silu
#pragma unroll
    for (int j0 = 0; j0 < 64; j0 += 8) {
        float acc[8] = {0.f, 0.f, 0.f, 0.f, 0.f, 0.f, 0.f, 0.f};
#pragma unroll
        for (int k = 0; k < 64; ++k) {
            float av = b[k];
#pragma unroll
            for (int jj = 0; jj < 8; ++jj) acc[jj] += av * W3[k * 64 + j0 + jj];
        }
#pragma unroll
        for (int jj = 0; jj < 8; ++jj) a[j0 + jj] = silu(acc[jj] * 0.125f);
    }

    // layer 4: [64] -> [192], scale 1/8, no activation; store bf16
    unsigned short* mrow = mix + (size_t)e * MIXW;
#pragma unroll
    for (int j0 = 0; j0 < MIXW; j0 += 8) {
        float acc[8] = {0.f, 0.f, 0.f, 0.f, 0.f, 0.f, 0.f, 0.f};
#pragma unroll
        for (int k = 0; k < 64; ++k) {
            float av = a[k];
#pragma unroll
            for (int jj = 0; jj < 8; ++jj) acc[jj] += av * W4[k * MIXW + j0 + jj];
        }
        union { unsigned short us[8]; uint4 v; } pk;
#pragma unroll
        for (int jj = 0; jj < 8; ++jj) pk.us[jj] = f2bf(acc[jj] * 0.125f);
        *((uint4*)(mrow + j0)) = pk.v;
    }
}

// ---------- K3a: receiver histogram ----------
__global__ __launch_bounds__(256) void k_hist(const int* __restrict__ recv,
                                              int* __restrict__ counts) {
    int e = blockIdx.x * 256 + threadIdx.x;
    atomicAdd(&counts[recv[e]], 1);
}

// ---------- K3b: single-block exclusive scan over counts ----------
__global__ __launch_bounds__(1024) void k_scan(const int* __restrict__ counts,
                                               int* __restrict__ offsets,
                                               int* __restrict__ cursor) {
    __shared__ int part[1024];
    int t = threadIdx.x;
    const int CHUNK = 10;  // 1024*10 >= 10000
    int base = t * CHUNK;
    int s = 0;
    for (int i = 0; i < CHUNK; ++i) {
        int idx = base + i;
        if (idx < N_NODES) s += counts[idx];
    }
    part[t] = s;
    __syncthreads();
    for (int off = 1; off < 1024; off <<= 1) {
        int v = 0;
        if (t >= off) v = part[t - off];
        __syncthreads();
        part[t] += v;
        __syncthreads();
    }
    int run = part[t] - s;  // exclusive base for this chunk
    for (int i = 0; i < CHUNK; ++i) {
        int idx = base + i;
        if (idx < N_NODES) {
            offsets[idx] = run;
            cursor[idx] = run;
            run += counts[idx];
        }
    }
    if (t == 1023) offsets[N_NODES] = part[1023];
}

// ---------- K3c: scatter edge ids into CSR order ----------
__global__ __launch_bounds__(256) void k_scatter(const int* __restrict__ recv,
                                                 int* __restrict__ cursor,
                                                 int* __restrict__ eids) {
    int e = blockIdx.x * 256 + threadIdx.x;
    int pos = atomicAdd(&cursor[recv[e]], 1);
    eids[pos] = e;
}

// ---------- K4: per-node aggregation (one wave per node, lane = channel) ----------
__global__ __launch_bounds__(256) void k_agg(const int* __restrict__ offsets,
                                             const int* __restrict__ eids,
                                             const int* __restrict__ senders,
                                             const float* __restrict__ h,
                                             const float* __restrict__ shb,
                                             const unsigned short* __restrict__ mix,
                                             float* __restrict__ agg) {
    int node = __builtin_amdgcn_readfirstlane(blockIdx.x * 4 + (threadIdx.x >> 6));
    int lane = threadIdx.x & 63;
    int s0 = __builtin_amdgcn_readfirstlane(offsets[node]);
    int s1 = __builtin_amdgcn_readfirstlane(offsets[node + 1]);
    float acc[9] = {0.f, 0.f, 0.f, 0.f, 0.f, 0.f, 0.f, 0.f, 0.f};
    for (int i = s0; i < s1; ++i) {
        int eid = __builtin_amdgcn_readfirstlane(eids[i]);
        int s = __builtin_amdgcn_readfirstlane(senders[eid]);
        float hv = h[(size_t)s * CH + lane];
        const unsigned short* mrow = mix + (size_t)eid * MIXW;
        float w0 = bf2f(mrow[lane]);
        float w1 = bf2f(mrow[64 + lane]);
        float w2 = bf2f(mrow[128 + lane]);
        const float* shp = shb + (size_t)eid * SH_PAD;
        float h0 = hv * w0, h1 = hv * w1, h2 = hv * w2;
        acc[0] += h0 * shp[0];
        acc[1] += h1 * shp[1];
        acc[2] += h1 * shp[2];
        acc[3] += h1 * shp[3];
        acc[4] += h2 * shp[4];
        acc[5] += h2 * shp[5];
        acc[6] += h2 * shp[6];
        acc[7] += h2 * shp[7];
        acc[8] += h2 * shp[8];
    }
    float* arow = agg + (size_t)node * 576 + lane * 9;
#pragma unroll
    for (int m = 0; m < 9; ++m) arow[m] = acc[m] * (1.0f / 32.0f);
}

// ---------- K5: linear_down per l ----------
__global__ __launch_bounds__(256) void k_down(const float* __restrict__ agg,
                                              const float* __restrict__ Wd,
                                              float* __restrict__ out) {
    int node = __builtin_amdgcn_readfirstlane(blockIdx.x * 4 + (threadIdx.x >> 6));
    int lane = threadIdx.x & 63;  // = output channel d
    const float* arow = agg + (size_t)node * 576;  // [c][m], m-fastest (9)
    float* orow = out + (size_t)node * 576;

    // l = 0 (m = 0), cols 0..63
    {
        float acc = 0.f;
#pragma unroll
        for (int c = 0; c < 64; ++c) acc += arow[c * 9 + 0] * Wd[c * 64 + lane];
        orow[lane] = acc * 0.125f;
    }
    // l = 1 (m = 1..3), cols 64 + d*3 + mm
#pragma unroll
    for (int mm = 0; mm < 3; ++mm) {
        float acc = 0.f;
#pragma unroll
        for (int c = 0; c < 64; ++c) acc += arow[c * 9 + 1 + mm] * Wd[(64 + c) * 64 + lane];
        orow[64 + lane * 3 + mm] = acc * 0.125f;
    }
    // l = 2 (m = 4..8), cols 256 + d*5 + mm
#pragma unroll
    for (int mm = 0; mm < 5; ++mm) {
        float acc = 0.f;
#pragma unroll
        for (int c = 0; c < 64; ++c) acc += arow[c * 9 + 4 + mm] * Wd[(128 + c) * 64 + lane];
        orow[256 + lane * 5 + mm] = acc * 0.125f;
    }
}

// ---------- launcher ----------
static inline size_t align256(size_t x) { return (x + 255) & ~(size_t)255; }

extern "C" void kernel_launch(void* const* d_in, const int* in_sizes, int n_in,
                              void* d_out, int out_size, void* d_ws, size_t ws_size,
                              hipStream_t stream) {
    const float* edge_vectors = (const float*)d_in[0];
    const float* node_feats   = (const float*)d_in[1];
    const float* radial       = (const float*)d_in[2];
    const int*   senders      = (const int*)d_in[3];
    const int*   receivers    = (const int*)d_in[4];
    const float* W_up         = (const float*)d_in[5];
    const float* W_mlp1       = (const float*)d_in[6];
    const float* W_mlp2       = (const float*)d_in[7];
    const float* W_mlp3       = (const float*)d_in[8];
    const float* W_mlp4       = (const float*)d_in[9];
    const float* W_down       = (const float*)d_in[10];
    float* out = (float*)d_out;

    char* base = (char*)d_ws;
    size_t off = 0;
    float* h = (float*)(base + off);              off = align256(off + (size_t)N_NODES * CH * 4);
    float* shb = (float*)(base + off);            off = align256(off + (size_t)N_EDGES * SH_PAD * 4);
    unsigned short* mix = (unsigned short*)(base + off); off = align256(off + (size_t)N_EDGES * MIXW * 2);
    float* agg = (float*)(base + off);            off = align256(off + (size_t)N_NODES * 576 * 4);
    int* counts = (int*)(base + off);             off = align256(off + (size_t)N_NODES * 4);
    int* offsets = (int*)(base + off);            off = align256(off + (size_t)(N_NODES + 1) * 4);
    int* cursor = (int*)(base + off);             off = align256(off + (size_t)N_NODES * 4);
    int* eids = (int*)(base + off);               off = align256(off + (size_t)N_EDGES * 4);

    hipMemsetAsync(counts, 0, (size_t)N_NODES * 4, stream);

    k_h<<<N_NODES / 4, 256, 0, stream>>>(node_feats, W_up, h);
    k_edge<<<N_EDGES / 256, 256, 0, stream>>>(edge_vectors, radial, W_mlp1, W_mlp2, W_mlp3,
                                              W_mlp4, shb, mix);
    k_hist<<<N_EDGES / 256, 256, 0, stream>>>(receivers, counts);
    k_scan<<<1, 1024, 0, stream>>>(counts, offsets, cursor);
    k_scatter<<<N_EDGES / 256, 256, 0, stream>>>(receivers, cursor, eids);
    k_agg<<<N_NODES / 4, 256, 0, stream>>>(offsets, eids, senders, h, shb, mix, agg);
    k_down<<<N_NODES / 4, 256, 0, stream>>>(agg, W_down, out);
}

// Round 2
// 1692.910 us; speedup vs baseline: 2.2934x; 2.2934x over previous
//
#include <hip/hip_runtime.h>
#include <hip/hip_bf16.h>
#include <math.h>

#define N_NODES 10000
#define N_EDGES 320000
#define CH 64
#define SH_PAD 12   // sh stored padded to 12 floats/row for 16B-aligned stores
#define MIXW 192    // N_L * CH

// ---------- small helpers ----------
__device__ __forceinline__ float bf2f(unsigned short u) {
    union { unsigned int i; float f; } v; v.i = ((unsigned int)u) << 16; return v.f;
}
__device__ __forceinline__ unsigned short f2bf(float f) {
    unsigned int x = __float_as_uint(f);
    unsigned int r = x + 0x7fffu + ((x >> 16) & 1u);   // RNE
    return (unsigned short)(r >> 16);
}
__device__ __forceinline__ float silu(float t) {
    return t / (1.0f + __expf(-t));
}

// ---------- K1: h = (node_feats @ W_up) / 8 ----------
__global__ __launch_bounds__(256) void k_h(const float* __restrict__ nf,
                                           const float* __restrict__ Wup,
                                           float* __restrict__ h) {
    int node = __builtin_amdgcn_readfirstlane(blockIdx.x * 4 + (threadIdx.x >> 6));
    int lane = threadIdx.x & 63;
    const float* nrow = nf + (size_t)node * CH;
    float acc = 0.f;
#pragma unroll
    for (int k = 0; k < CH; ++k) acc += nrow[k] * Wup[k * CH + lane];
    h[(size_t)node * CH + lane] = acc * 0.125f;
}

// ---------- K_e1: spherical harmonics + MLP layer1 + layer2 ----------
// Live set: r[8] + a[64] + acc[8] ~ 80 VGPRs -> no spill.
__global__ __launch_bounds__(256, 2) void k_e1(const float* __restrict__ ev,
                                               const float* __restrict__ rad,
                                               const float* __restrict__ W1,
                                               const float* __restrict__ W2,
                                               float* __restrict__ shb,
                                               unsigned short* __restrict__ act) {
    int e = blockIdx.x * 256 + threadIdx.x;

    // --- spherical harmonics (component-normalized, l<=2) ---
    float vx = ev[(size_t)e * 3 + 0], vy = ev[(size_t)e * 3 + 1], vz = ev[(size_t)e * 3 + 2];
    float inv = rsqrtf(vx * vx + vy * vy + vz * vz);
    float x = vx * inv, y = vy * inv, z = vz * inv;
    const float s3 = 1.7320508075688772f;
    const float s15 = 3.872983346207417f;
    const float s5 = 2.2360679774997896f;
    float4* sp = (float4*)(shb + (size_t)e * SH_PAD);
    sp[0] = make_float4(1.0f, s3 * x, s3 * y, s3 * z);
    sp[1] = make_float4(s15 * x * y, s15 * y * z, 0.5f * s5 * (3.0f * z * z - 1.0f), s15 * x * z);
    sp[2] = make_float4(0.5f * s15 * (x * x - y * y), 0.f, 0.f, 0.f);

    // --- layer 1: [8] -> [64], scale 1/sqrt(8), silu ---
    const float4* rp = (const float4*)(rad + (size_t)e * 8);
    float4 r01 = rp[0], r23 = rp[1];
    float r[8] = { r01.x, r01.y, r01.z, r01.w, r23.x, r23.y, r23.z, r23.w };

    float a[64];
#pragma unroll
    for (int j = 0; j < 64; ++j) {
        float t = 0.f;
#pragma unroll
        for (int k = 0; k < 8; ++k) t += r[k] * W1[k * 64 + j];
        a[j] = silu(t * 0.3535533905932738f);
    }

    // --- layer 2: [64] -> [64], scale 1/8, silu; stream out bf16 in 8-chunks ---
    unsigned short* arow = act + (size_t)e * 64;
#pragma unroll
    for (int j0 = 0; j0 < 64; j0 += 8) {
        float acc[8] = {0.f, 0.f, 0.f, 0.f, 0.f, 0.f, 0.f, 0.f};
#pragma unroll
        for (int k = 0; k < 64; ++k) {
            float av = a[k];
#pragma unroll
            for (int jj = 0; jj < 8; ++jj) acc[jj] += av * W2[k * 64 + j0 + jj];
        }
        union { unsigned short us[8]; uint4 v; } pk;
#pragma unroll
        for (int jj = 0; jj < 8; ++jj) pk.us[jj] = f2bf(silu(acc[jj] * 0.125f));
        *((uint4*)(arow + j0)) = pk.v;
    }
}

// ---------- K_e2: MLP layer3, in-place on act ----------
__global__ __launch_bounds__(256, 2) void k_e2(const float* __restrict__ W3,
                                               unsigned short* __restrict__ act) {
    int e = blockIdx.x * 256 + threadIdx.x;
    unsigned short* arow = act + (size_t)e * 64;

    float a[64];
#pragma unroll
    for (int j0 = 0; j0 < 64; j0 += 8) {
        union { unsigned short us[8]; uint4 v; } pk;
        pk.v = *((const uint4*)(arow + j0));
#pragma unroll
        for (int jj = 0; jj < 8; ++jj) a[j0 + jj] = bf2f(pk.us[jj]);
    }

#pragma unroll
    for (int j0 = 0; j0 < 64; j0 += 8) {
        float acc[8] = {0.f, 0.f, 0.f, 0.f, 0.f, 0.f, 0.f, 0.f};
#pragma unroll
        for (int k = 0; k < 64; ++k) {
            float av = a[k];
#pragma unroll
            for (int jj = 0; jj < 8; ++jj) acc[jj] += av * W3[k * 64 + j0 + jj];
        }
        union { unsigned short us[8]; uint4 v; } pk;
#pragma unroll
        for (int jj = 0; jj < 8; ++jj) pk.us[jj] = f2bf(silu(acc[jj] * 0.125f));
        *((uint4*)(arow + j0)) = pk.v;
    }
}

// ---------- K_e3: MLP layer4 -> mix (bf16) ----------
__global__ __launch_bounds__(256, 2) void k_e3(const float* __restrict__ W4,
                                               const unsigned short* __restrict__ act,
                                               unsigned short* __restrict__ mix) {
    int e = blockIdx.x * 256 + threadIdx.x;
    const unsigned short* arow = act + (size_t)e * 64;

    float a[64];
#pragma unroll
    for (int j0 = 0; j0 < 64; j0 += 8) {
        union { unsigned short us[8]; uint4 v; } pk;
        pk.v = *((const uint4*)(arow + j0));
#pragma unroll
        for (int jj = 0; jj < 8; ++jj) a[j0 + jj] = bf2f(pk.us[jj]);
    }

    unsigned short* mrow = mix + (size_t)e * MIXW;
#pragma unroll
    for (int j0 = 0; j0 < MIXW; j0 += 8) {
        float acc[8] = {0.f, 0.f, 0.f, 0.f, 0.f, 0.f, 0.f, 0.f};
#pragma unroll
        for (int k = 0; k < 64; ++k) {
            float av = a[k];
#pragma unroll
            for (int jj = 0; jj < 8; ++jj) acc[jj] += av * W4[k * MIXW + j0 + jj];
        }
        union { unsigned short us[8]; uint4 v; } pk;
#pragma unroll
        for (int jj = 0; jj < 8; ++jj) pk.us[jj] = f2bf(acc[jj] * 0.125f);
        *((uint4*)(mrow + j0)) = pk.v;
    }
}

// ---------- K3a: receiver histogram ----------
__global__ __launch_bounds__(256) void k_hist(const int* __restrict__ recv,
                                              int* __restrict__ counts) {
    int e = blockIdx.x * 256 + threadIdx.x;
    atomicAdd(&counts[recv[e]], 1);
}

// ---------- K3b: single-block exclusive scan over counts ----------
__global__ __launch_bounds__(1024) void k_scan(const int* __restrict__ counts,
                                               int* __restrict__ offsets,
                                               int* __restrict__ cursor) {
    __shared__ int part[1024];
    int t = threadIdx.x;
    const int CHUNK = 10;  // 1024*10 >= 10000
    int base = t * CHUNK;
    int s = 0;
    for (int i = 0; i < CHUNK; ++i) {
        int idx = base + i;
        if (idx < N_NODES) s += counts[idx];
    }
    part[t] = s;
    __syncthreads();
    for (int off = 1; off < 1024; off <<= 1) {
        int v = 0;
        if (t >= off) v = part[t - off];
        __syncthreads();
        part[t] += v;
        __syncthreads();
    }
    int run = part[t] - s;  // exclusive base for this chunk
    for (int i = 0; i < CHUNK; ++i) {
        int idx = base + i;
        if (idx < N_NODES) {
            offsets[idx] = run;
            cursor[idx] = run;
            run += counts[idx];
        }
    }
    if (t == 1023) offsets[N_NODES] = part[1023];
}

// ---------- K3c: scatter edge ids into CSR order ----------
__global__ __launch_bounds__(256) void k_scatter(const int* __restrict__ recv,
                                                 int* __restrict__ cursor,
                                                 int* __restrict__ eids) {
    int e = blockIdx.x * 256 + threadIdx.x;
    int pos = atomicAdd(&cursor[recv[e]], 1);
    eids[pos] = e;
}

// ---------- K4: per-node aggregation (one wave per node, lane = channel) ----------
__global__ __launch_bounds__(256) void k_agg(const int* __restrict__ offsets,
                                             const int* __restrict__ eids,
                                             const int* __restrict__ senders,
                                             const float* __restrict__ h,
                                             const float* __restrict__ shb,
                                             const unsigned short* __restrict__ mix,
                                             float* __restrict__ agg) {
    int node = __builtin_amdgcn_readfirstlane(blockIdx.x * 4 + (threadIdx.x >> 6));
    int lane = threadIdx.x & 63;
    int s0 = __builtin_amdgcn_readfirstlane(offsets[node]);
    int s1 = __builtin_amdgcn_readfirstlane(offsets[node + 1]);
    float acc[9] = {0.f, 0.f, 0.f, 0.f, 0.f, 0.f, 0.f, 0.f, 0.f};
    for (int i = s0; i < s1; ++i) {
        int eid = __builtin_amdgcn_readfirstlane(eids[i]);
        int s = __builtin_amdgcn_readfirstlane(senders[eid]);
        float hv = h[(size_t)s * CH + lane];
        const unsigned short* mrow = mix + (size_t)eid * MIXW;
        float w0 = bf2f(mrow[lane]);
        float w1 = bf2f(mrow[64 + lane]);
        float w2 = bf2f(mrow[128 + lane]);
        const float* shp = shb + (size_t)eid * SH_PAD;
        float h0 = hv * w0, h1 = hv * w1, h2 = hv * w2;
        acc[0] += h0 * shp[0];
        acc[1] += h1 * shp[1];
        acc[2] += h1 * shp[2];
        acc[3] += h1 * shp[3];
        acc[4] += h2 * shp[4];
        acc[5] += h2 * shp[5];
        acc[6] += h2 * shp[6];
        acc[7] += h2 * shp[7];
        acc[8] += h2 * shp[8];
    }
    float* arow = agg + (size_t)node * 576 + lane * 9;
#pragma unroll
    for (int m = 0; m < 9; ++m) arow[m] = acc[m] * (1.0f / 32.0f);
}

// ---------- K5: linear_down per l ----------
__global__ __launch_bounds__(256) void k_down(const float* __restrict__ agg,
                                              const float* __restrict__ Wd,
                                              float* __restrict__ out) {
    int node = __builtin_amdgcn_readfirstlane(blockIdx.x * 4 + (threadIdx.x >> 6));
    int lane = threadIdx.x & 63;  // = output channel d
    const float* arow = agg + (size_t)node * 576;  // [c][m], m-fastest (9)
    float* orow = out + (size_t)node * 576;

    // l = 0 (m = 0), cols 0..63
    {
        float acc = 0.f;
#pragma unroll
        for (int c = 0; c < 64; ++c) acc += arow[c * 9 + 0] * Wd[c * 64 + lane];
        orow[lane] = acc * 0.125f;
    }
    // l = 1 (m = 1..3), cols 64 + d*3 + mm
#pragma unroll
    for (int mm = 0; mm < 3; ++mm) {
        float acc = 0.f;
#pragma unroll
        for (int c = 0; c < 64; ++c) acc += arow[c * 9 + 1 + mm] * Wd[(64 + c) * 64 + lane];
        orow[64 + lane * 3 + mm] = acc * 0.125f;
    }
    // l = 2 (m = 4..8), cols 256 + d*5 + mm
#pragma unroll
    for (int mm = 0; mm < 5; ++mm) {
        float acc = 0.f;
#pragma unroll
        for (int c = 0; c < 64; ++c) acc += arow[c * 9 + 4 + mm] * Wd[(128 + c) * 64 + lane];
        orow[256 + lane * 5 + mm] = acc * 0.125f;
    }
}

// ---------- launcher ----------
static inline size_t align256(size_t x) { return (x + 255) & ~(size_t)255; }

extern "C" void kernel_launch(void* const* d_in, const int* in_sizes, int n_in,
                              void* d_out, int out_size, void* d_ws, size_t ws_size,
                              hipStream_t stream) {
    const float* edge_vectors = (const float*)d_in[0];
    const float* node_feats   = (const float*)d_in[1];
    const float* radial       = (const float*)d_in[2];
    const int*   senders      = (const int*)d_in[3];
    const int*   receivers    = (const int*)d_in[4];
    const float* W_up         = (const float*)d_in[5];
    const float* W_mlp1       = (const float*)d_in[6];
    const float* W_mlp2       = (const float*)d_in[7];
    const float* W_mlp3       = (const float*)d_in[8];
    const float* W_mlp4       = (const float*)d_in[9];
    const float* W_down       = (const float*)d_in[10];
    float* out = (float*)d_out;

    char* base = (char*)d_ws;
    size_t off = 0;
    float* h = (float*)(base + off);              off = align256(off + (size_t)N_NODES * CH * 4);
    float* shb = (float*)(base + off);            off = align256(off + (size_t)N_EDGES * SH_PAD * 4);
    unsigned short* mix = (unsigned short*)(base + off); off = align256(off + (size_t)N_EDGES * MIXW * 2);
    unsigned short* act = (unsigned short*)(base + off); off = align256(off + (size_t)N_EDGES * 64 * 2);
    float* agg = (float*)(base + off);            off = align256(off + (size_t)N_NODES * 576 * 4);
    int* counts = (int*)(base + off);             off = align256(off + (size_t)N_NODES * 4);
    int* offsets = (int*)(base + off);            off = align256(off + (size_t)(N_NODES + 1) * 4);
    int* cursor = (int*)(base + off);             off = align256(off + (size_t)N_NODES * 4);
    int* eids = (int*)(base + off);               off = align256(off + (size_t)N_EDGES * 4);

    hipMemsetAsync(counts, 0, (size_t)N_NODES * 4, stream);

    k_h<<<N_NODES / 4, 256, 0, stream>>>(node_feats, W_up, h);
    k_e1<<<N_EDGES / 256, 256, 0, stream>>>(edge_vectors, radial, W_mlp1, W_mlp2, shb, act);
    k_e2<<<N_EDGES / 256, 256, 0, stream>>>(W_mlp3, act);
    k_e3<<<N_EDGES / 256, 256, 0, stream>>>(W_mlp4, act, mix);
    k_hist<<<N_EDGES / 256, 256, 0, stream>>>(receivers, counts);
    k_scan<<<1, 1024, 0, stream>>>(counts, offsets, cursor);
    k_scatter<<<N_EDGES / 256, 256, 0, stream>>>(receivers, cursor, eids);
    k_agg<<<N_NODES / 4, 256, 0, stream>>>(offsets, eids, senders, h, shb, mix, agg);
    k_down<<<N_NODES / 4, 256, 0, stream>>>(agg, W_down, out);
}

// Round 3
// 344.947 us; speedup vs baseline: 11.2556x; 4.9077x over previous
//
#include <hip/hip_runtime.h>
#include <hip/hip_bf16.h>
#include <math.h>

#define N_NODES 10000
#define N_EDGES 320000
#define CH 64
#define SH_PAD 12   // sh stored padded to 12 floats/row for 16B-aligned stores
#define MIXW 192    // N_L * CH

typedef __attribute__((ext_vector_type(8))) short bf16x8;
typedef __attribute__((ext_vector_type(4))) float f32x4;
#define MFMA16(a, b, c) __builtin_amdgcn_mfma_f32_16x16x32_bf16(a, b, c, 0, 0, 0)

// ---------- small helpers ----------
__device__ __forceinline__ float bf2f(unsigned short u) {
    union { unsigned int i; float f; } v; v.i = ((unsigned int)u) << 16; return v.f;
}
__device__ __forceinline__ unsigned short f2bf(float f) {
    unsigned int x = __float_as_uint(f);
    unsigned int r = x + 0x7fffu + ((x >> 16) & 1u);   // RNE
    return (unsigned short)(r >> 16);
}
__device__ __forceinline__ float silu(float t) {
    return t / (1.0f + __expf(-t));
}

// ---------- K1: h = (node_feats @ W_up) / 8 ----------
__global__ __launch_bounds__(256) void k_h(const float* __restrict__ nf,
                                           const float* __restrict__ Wup,
                                           float* __restrict__ h) {
    int node = __builtin_amdgcn_readfirstlane(blockIdx.x * 4 + (threadIdx.x >> 6));
    int lane = threadIdx.x & 63;
    const float* nrow = nf + (size_t)node * CH;
    float acc = 0.f;
#pragma unroll
    for (int k = 0; k < CH; ++k) acc += nrow[k] * Wup[k * CH + lane];
    h[(size_t)node * CH + lane] = acc * 0.125f;
}

// ---------- K_mlp: fused SH + radial MLP (all 4 layers) via bf16 MFMA ----------
// Block = 256 threads = 4 waves; 64 edges/block (16 per wave).
// LDS (shorts): [0..13824)   weights, phased: A: W1t[64][8] + W2t[64][72]
//                                              B: W3t[64][72]   C: W4t[192][72]
//               [13824..18432) act[64][72]  (bf16 activations, k-stride 72)
//               [18432..30720) stage[64][192] (L4 output, then coalesced copy-out)
__global__ __launch_bounds__(256, 2) void k_mlp(const float* __restrict__ ev,
                                                const float* __restrict__ rad,
                                                const float* __restrict__ W1,
                                                const float* __restrict__ W2,
                                                const float* __restrict__ W3,
                                                const float* __restrict__ W4,
                                                float* __restrict__ shb,
                                                unsigned short* __restrict__ mix) {
    __shared__ unsigned short s_lds[30720];
    unsigned short* act = s_lds + 13824;
    unsigned short* stg = s_lds + 18432;

    const int t = threadIdx.x;
    const int e0 = blockIdx.x * 64;
    const int wv = t >> 6;
    const int lane = t & 63;
    const int lrow = lane & 15;
    const int quad = lane >> 4;
    const int em = wv * 16 + lrow;               // A-frag row (edge within block)
    const int crow0 = wv * 16 + quad * 4;        // C rows base (edge within block)

    // ---- phase A staging: W1t + W2t (bf16, transposed, k-stride 72/8) ----
    for (int i = t; i < 512; i += 256) {
        int k = i >> 6, n = i & 63;
        s_lds[n * 8 + k] = (unsigned short)f2bf(W1[i]);
    }
    for (int i = t; i < 4096; i += 256) {
        int k = i >> 6, n = i & 63;
        s_lds[512 + n * 72 + k] = (unsigned short)f2bf(W2[i]);
    }

    // ---- spherical harmonics for this block's 64 edges ----
    if (t < 64) {
        int e = e0 + t;
        float vx = ev[(size_t)e * 3 + 0], vy = ev[(size_t)e * 3 + 1], vz = ev[(size_t)e * 3 + 2];
        float inv = rsqrtf(vx * vx + vy * vy + vz * vz);
        float x = vx * inv, y = vy * inv, z = vz * inv;
        const float s3 = 1.7320508075688772f;
        const float s15 = 3.872983346207417f;
        const float s5 = 2.2360679774997896f;
        float4* sp = (float4*)(shb + (size_t)e * SH_PAD);
        sp[0] = make_float4(1.0f, s3 * x, s3 * y, s3 * z);
        sp[1] = make_float4(s15 * x * y, s15 * y * z, 0.5f * s5 * (3.0f * z * z - 1.0f), s15 * x * z);
        sp[2] = make_float4(0.5f * s15 * (x * x - y * y), 0.f, 0.f, 0.f);
    }

    // ---- radial A-frag (K=8, quads 1-3 hold zeros) ----
    bf16x8 ar = {0, 0, 0, 0, 0, 0, 0, 0};
    if (quad == 0) {
        const float4* rp = (const float4*)(rad + (size_t)(e0 + em) * 8);
        float4 u = rp[0], v = rp[1];
        ar[0] = (short)f2bf(u.x); ar[1] = (short)f2bf(u.y);
        ar[2] = (short)f2bf(u.z); ar[3] = (short)f2bf(u.w);
        ar[4] = (short)f2bf(v.x); ar[5] = (short)f2bf(v.y);
        ar[6] = (short)f2bf(v.z); ar[7] = (short)f2bf(v.w);
    }
    __syncthreads();

    // ---- layer 1: [8]->[64], scale 1/sqrt(8), silu ----
#pragma unroll
    for (int nt = 0; nt < 4; ++nt) {
        bf16x8 bw = {0, 0, 0, 0, 0, 0, 0, 0};
        if (quad == 0) bw = *(const bf16x8*)(s_lds + (nt * 16 + lrow) * 8);
        f32x4 cc = {0.f, 0.f, 0.f, 0.f};
        cc = MFMA16(ar, bw, cc);
#pragma unroll
        for (int r = 0; r < 4; ++r)
            act[(crow0 + r) * 72 + nt * 16 + lrow] =
                (unsigned short)f2bf(silu(cc[r] * 0.3535533905932738f));
    }

    // ---- layer 2: [64]->[64], scale 1/8, silu (in-place on act) ----
    {
        bf16x8 a0 = *(const bf16x8*)(act + em * 72 + quad * 8);
        bf16x8 a1 = *(const bf16x8*)(act + em * 72 + 32 + quad * 8);
#pragma unroll
        for (int nt = 0; nt < 4; ++nt) {
            const unsigned short* wr = s_lds + 512 + (nt * 16 + lrow) * 72 + quad * 8;
            bf16x8 b0 = *(const bf16x8*)wr;
            bf16x8 b1 = *(const bf16x8*)(wr + 32);
            f32x4 cc = {0.f, 0.f, 0.f, 0.f};
            cc = MFMA16(a0, b0, cc);
            cc = MFMA16(a1, b1, cc);
#pragma unroll
            for (int r = 0; r < 4; ++r)
                act[(crow0 + r) * 72 + nt * 16 + lrow] =
                    (unsigned short)f2bf(silu(cc[r] * 0.125f));
        }
    }
    __syncthreads();

    // ---- phase B staging: W3t over weight region ----
    for (int i = t; i < 4096; i += 256) {
        int k = i >> 6, n = i & 63;
        s_lds[n * 72 + k] = (unsigned short)f2bf(W3[i]);
    }
    __syncthreads();

    // ---- layer 3: [64]->[64], scale 1/8, silu (in-place on act) ----
    {
        bf16x8 a0 = *(const bf16x8*)(act + em * 72 + quad * 8);
        bf16x8 a1 = *(const bf16x8*)(act + em * 72 + 32 + quad * 8);
#pragma unroll
        for (int nt = 0; nt < 4; ++nt) {
            const unsigned short* wr = s_lds + (nt * 16 + lrow) * 72 + quad * 8;
            bf16x8 b0 = *(const bf16x8*)wr;
            bf16x8 b1 = *(const bf16x8*)(wr + 32);
            f32x4 cc = {0.f, 0.f, 0.f, 0.f};
            cc = MFMA16(a0, b0, cc);
            cc = MFMA16(a1, b1, cc);
#pragma unroll
            for (int r = 0; r < 4; ++r)
                act[(crow0 + r) * 72 + nt * 16 + lrow] =
                    (unsigned short)f2bf(silu(cc[r] * 0.125f));
        }
    }
    __syncthreads();

    // ---- phase C staging: W4t [192][72] ----
    for (int i = t; i < 12288; i += 256) {
        int k = i / 192, n = i % 192;
        s_lds[n * 72 + k] = (unsigned short)f2bf(W4[i]);
    }
    __syncthreads();

    // ---- layer 4: [64]->[192], scale 1/8, no activation -> stage ----
    {
        bf16x8 a0 = *(const bf16x8*)(act + em * 72 + quad * 8);
        bf16x8 a1 = *(const bf16x8*)(act + em * 72 + 32 + quad * 8);
#pragma unroll
        for (int nt = 0; nt < 12; ++nt) {
            const unsigned short* wr = s_lds + (nt * 16 + lrow) * 72 + quad * 8;
            bf16x8 b0 = *(const bf16x8*)wr;
            bf16x8 b1 = *(const bf16x8*)(wr + 32);
            f32x4 cc = {0.f, 0.f, 0.f, 0.f};
            cc = MFMA16(a0, b0, cc);
            cc = MFMA16(a1, b1, cc);
#pragma unroll
            for (int r = 0; r < 4; ++r)
                stg[(crow0 + r) * 192 + nt * 16 + lrow] =
                    (unsigned short)f2bf(cc[r] * 0.125f);
        }
    }
    __syncthreads();

    // ---- coalesced copy-out: stage [64][192] bf16 -> mix ----
    {
        const uint4* sp = (const uint4*)stg;
        uint4* gp = (uint4*)(mix + (size_t)e0 * MIXW);
        for (int i = t; i < 1536; i += 256) gp[i] = sp[i];
    }
}

// ---------- K3a: receiver histogram ----------
__global__ __launch_bounds__(256) void k_hist(const int* __restrict__ recv,
                                              int* __restrict__ counts) {
    int e = blockIdx.x * 256 + threadIdx.x;
    atomicAdd(&counts[recv[e]], 1);
}

// ---------- K3b: single-block exclusive scan over counts ----------
__global__ __launch_bounds__(1024) void k_scan(const int* __restrict__ counts,
                                               int* __restrict__ offsets,
                                               int* __restrict__ cursor) {
    __shared__ int part[1024];
    int t = threadIdx.x;
    const int CHUNK = 10;  // 1024*10 >= 10000
    int base = t * CHUNK;
    int s = 0;
    for (int i = 0; i < CHUNK; ++i) {
        int idx = base + i;
        if (idx < N_NODES) s += counts[idx];
    }
    part[t] = s;
    __syncthreads();
    for (int off = 1; off < 1024; off <<= 1) {
        int v = 0;
        if (t >= off) v = part[t - off];
        __syncthreads();
        part[t] += v;
        __syncthreads();
    }
    int run = part[t] - s;  // exclusive base for this chunk
    for (int i = 0; i < CHUNK; ++i) {
        int idx = base + i;
        if (idx < N_NODES) {
            offsets[idx] = run;
            cursor[idx] = run;
            run += counts[idx];
        }
    }
    if (t == 1023) offsets[N_NODES] = part[1023];
}

// ---------- K3c: scatter edge ids into CSR order ----------
__global__ __launch_bounds__(256) void k_scatter(const int* __restrict__ recv,
                                                 int* __restrict__ cursor,
                                                 int* __restrict__ eids) {
    int e = blockIdx.x * 256 + threadIdx.x;
    int pos = atomicAdd(&cursor[recv[e]], 1);
    eids[pos] = e;
}

// ---------- K4: per-node aggregation (one wave per node, lane = channel) ----------
__global__ __launch_bounds__(256) void k_agg(const int* __restrict__ offsets,
                                             const int* __restrict__ eids,
                                             const int* __restrict__ senders,
                                             const float* __restrict__ h,
                                             const float* __restrict__ shb,
                                             const unsigned short* __restrict__ mix,
                                             float* __restrict__ agg) {
    int node = __builtin_amdgcn_readfirstlane(blockIdx.x * 4 + (threadIdx.x >> 6));
    int lane = threadIdx.x & 63;
    int s0 = __builtin_amdgcn_readfirstlane(offsets[node]);
    int s1 = __builtin_amdgcn_readfirstlane(offsets[node + 1]);
    float acc[9] = {0.f, 0.f, 0.f, 0.f, 0.f, 0.f, 0.f, 0.f, 0.f};
    for (int i = s0; i < s1; ++i) {
        int eid = __builtin_amdgcn_readfirstlane(eids[i]);
        int s = __builtin_amdgcn_readfirstlane(senders[eid]);
        float hv = h[(size_t)s * CH + lane];
        const unsigned short* mrow = mix + (size_t)eid * MIXW;
        float w0 = bf2f(mrow[lane]);
        float w1 = bf2f(mrow[64 + lane]);
        float w2 = bf2f(mrow[128 + lane]);
        const float* shp = shb + (size_t)eid * SH_PAD;
        float h0 = hv * w0, h1 = hv * w1, h2 = hv * w2;
        acc[0] += h0 * shp[0];
        acc[1] += h1 * shp[1];
        acc[2] += h1 * shp[2];
        acc[3] += h1 * shp[3];
        acc[4] += h2 * shp[4];
        acc[5] += h2 * shp[5];
        acc[6] += h2 * shp[6];
        acc[7] += h2 * shp[7];
        acc[8] += h2 * shp[8];
    }
    float* arow = agg + (size_t)node * 576 + lane * 9;
#pragma unroll
    for (int m = 0; m < 9; ++m) arow[m] = acc[m] * (1.0f / 32.0f);
}

// ---------- K5: linear_down per l ----------
__global__ __launch_bounds__(256) void k_down(const float* __restrict__ agg,
                                              const float* __restrict__ Wd,
                                              float* __restrict__ out) {
    int node = __builtin_amdgcn_readfirstlane(blockIdx.x * 4 + (threadIdx.x >> 6));
    int lane = threadIdx.x & 63;  // = output channel d
    const float* arow = agg + (size_t)node * 576;  // [c][m], m-fastest (9)
    float* orow = out + (size_t)node * 576;

    // l = 0 (m = 0), cols 0..63
    {
        float acc = 0.f;
#pragma unroll
        for (int c = 0; c < 64; ++c) acc += arow[c * 9 + 0] * Wd[c * 64 + lane];
        orow[lane] = acc * 0.125f;
    }
    // l = 1 (m = 1..3), cols 64 + d*3 + mm
#pragma unroll
    for (int mm = 0; mm < 3; ++mm) {
        float acc = 0.f;
#pragma unroll
        for (int c = 0; c < 64; ++c) acc += arow[c * 9 + 1 + mm] * Wd[(64 + c) * 64 + lane];
        orow[64 + lane * 3 + mm] = acc * 0.125f;
    }
    // l = 2 (m = 4..8), cols 256 + d*5 + mm
#pragma unroll
    for (int mm = 0; mm < 5; ++mm) {
        float acc = 0.f;
#pragma unroll
        for (int c = 0; c < 64; ++c) acc += arow[c * 9 + 4 + mm] * Wd[(128 + c) * 64 + lane];
        orow[256 + lane * 5 + mm] = acc * 0.125f;
    }
}

// ---------- launcher ----------
static inline size_t align256(size_t x) { return (x + 255) & ~(size_t)255; }

extern "C" void kernel_launch(void* const* d_in, const int* in_sizes, int n_in,
                              void* d_out, int out_size, void* d_ws, size_t ws_size,
                              hipStream_t stream) {
    const float* edge_vectors = (const float*)d_in[0];
    const float* node_feats   = (const float*)d_in[1];
    const float* radial       = (const float*)d_in[2];
    const int*   senders      = (const int*)d_in[3];
    const int*   receivers    = (const int*)d_in[4];
    const float* W_up         = (const float*)d_in[5];
    const float* W_mlp1       = (const float*)d_in[6];
    const float* W_mlp2       = (const float*)d_in[7];
    const float* W_mlp3       = (const float*)d_in[8];
    const float* W_mlp4       = (const float*)d_in[9];
    const float* W_down       = (const float*)d_in[10];
    float* out = (float*)d_out;

    char* base = (char*)d_ws;
    size_t off = 0;
    float* h = (float*)(base + off);              off = align256(off + (size_t)N_NODES * CH * 4);
    float* shb = (float*)(base + off);            off = align256(off + (size_t)N_EDGES * SH_PAD * 4);
    unsigned short* mix = (unsigned short*)(base + off); off = align256(off + (size_t)N_EDGES * MIXW * 2);
    float* agg = (float*)(base + off);            off = align256(off + (size_t)N_NODES * 576 * 4);
    int* counts = (int*)(base + off);             off = align256(off + (size_t)N_NODES * 4);
    int* offsets = (int*)(base + off);            off = align256(off + (size_t)(N_NODES + 1) * 4);
    int* cursor = (int*)(base + off);             off = align256(off + (size_t)N_NODES * 4);
    int* eids = (int*)(base + off);               off = align256(off + (size_t)N_EDGES * 4);

    hipMemsetAsync(counts, 0, (size_t)N_NODES * 4, stream);

    k_h<<<N_NODES / 4, 256, 0, stream>>>(node_feats, W_up, h);
    k_mlp<<<N_EDGES / 64, 256, 0, stream>>>(edge_vectors, radial, W_mlp1, W_mlp2, W_mlp3,
                                            W_mlp4, shb, mix);
    k_hist<<<N_EDGES / 256, 256, 0, stream>>>(receivers, counts);
    k_scan<<<1, 1024, 0, stream>>>(counts, offsets, cursor);
    k_scatter<<<N_EDGES / 256, 256, 0, stream>>>(receivers, cursor, eids);
    k_agg<<<N_NODES / 4, 256, 0, stream>>>(offsets, eids, senders, h, shb, mix, agg);
    k_down<<<N_NODES / 4, 256, 0, stream>>>(agg, W_down, out);
}

// Round 5
// 302.895 us; speedup vs baseline: 12.8182x; 1.1388x over previous
//
#include <hip/hip_runtime.h>
#include <hip/hip_bf16.h>
#include <math.h>

#define N_NODES 10000
#define N_EDGES 320000
#define CH 64
#define SH_PAD 12   // sh stored padded to 12 floats/row for 16B-aligned stores
#define MIXW 192    // N_L * CH

// weight-image layout (shorts), stride-72 rows, matches LDS exactly
#define W1_OFF 0        // [64][8]
#define W2_OFF 512      // [64][72]
#define W3_OFF 5120     // [64][72]
#define W4_OFF 9728     // [192][72]
#define W_TOT 23552     // shorts (= 47104 bytes = 2944 uint4)
#define W_TOT_U4 2944   // uint4 count for staging memcpy  (R4 bug: was 1472)
#define ACT_STRIDE 72

typedef __attribute__((ext_vector_type(8))) short bf16x8;
typedef __attribute__((ext_vector_type(4))) float f32x4;
#define MFMA16(a, b, c) __builtin_amdgcn_mfma_f32_16x16x32_bf16(a, b, c, 0, 0, 0)

// ---------- small helpers ----------
__device__ __forceinline__ float bf2f(unsigned short u) {
    union { unsigned int i; float f; } v; v.i = ((unsigned int)u) << 16; return v.f;
}
__device__ __forceinline__ unsigned short f2bf(float f) {
    unsigned int x = __float_as_uint(f);
    unsigned int r = x + 0x7fffu + ((x >> 16) & 1u);   // RNE
    return (unsigned short)(r >> 16);
}
__device__ __forceinline__ float silu(float t) {
    return t / (1.0f + __expf(-t));
}

// ---------- K0: one-time weight convert/transpose to bf16 LDS image ----------
__global__ __launch_bounds__(256) void k_prep(const float* __restrict__ W1,
                                              const float* __restrict__ W2,
                                              const float* __restrict__ W3,
                                              const float* __restrict__ W4,
                                              unsigned short* __restrict__ wimg) {
    int i = blockIdx.x * 256 + threadIdx.x;
    if (i >= W_TOT) return;
    float v;
    if (i < W2_OFF) {
        int n = i >> 3, k = i & 7;
        v = W1[k * 64 + n];
    } else if (i < W3_OFF) {
        int j = i - W2_OFF; int n = j / 72, k = j % 72;
        v = (k < 64) ? W2[k * 64 + n] : 0.f;
    } else if (i < W4_OFF) {
        int j = i - W3_OFF; int n = j / 72, k = j % 72;
        v = (k < 64) ? W3[k * 64 + n] : 0.f;
    } else {
        int j = i - W4_OFF; int n = j / 72, k = j % 72;
        v = (k < 64) ? W4[k * MIXW + n] : 0.f;
    }
    wimg[i] = f2bf(v);
}

// ---------- K1: h = (node_feats @ W_up) / 8 ----------
__global__ __launch_bounds__(256) void k_h(const float* __restrict__ nf,
                                           const float* __restrict__ Wup,
                                           float* __restrict__ h) {
    int node = __builtin_amdgcn_readfirstlane(blockIdx.x * 4 + (threadIdx.x >> 6));
    int lane = threadIdx.x & 63;
    const float* nrow = nf + (size_t)node * CH;
    float acc = 0.f;
#pragma unroll
    for (int k = 0; k < CH; ++k) acc += nrow[k] * Wup[k * CH + lane];
    h[(size_t)node * CH + lane] = acc * 0.125f;
}

// ---------- K_mlp: fused SH + radial MLP via bf16 MFMA ----------
// 256 thr = 4 waves; 64 edges/block (16/wave). All weights LDS-resident.
// LDS shorts: [0, 23552) weight image (memcpy of wimg);
//             [23552, 28160) act[64][72] (per-wave 16-row ownership; also
//             reused as the L4 per-third stage -> NO inter-layer barriers).
__global__ __launch_bounds__(256, 2) void k_mlp(const float* __restrict__ ev,
                                                const float* __restrict__ rad,
                                                const unsigned short* __restrict__ wimg,
                                                float* __restrict__ shb,
                                                unsigned short* __restrict__ mix) {
    __shared__ unsigned short s_lds[28160];
    unsigned short* act = s_lds + W_TOT;

    const int t = threadIdx.x;
    const int e0 = blockIdx.x * 64;
    const int wv = t >> 6;
    const int lane = t & 63;
    const int lrow = lane & 15;
    const int quad = lane >> 4;
    const int em = wv * 16 + lrow;               // A-frag row (edge within block)
    const int crow0 = wv * 16 + quad * 4;        // C rows base

    // ---- weight staging: straight uint4 memcpy (2944 x 16B) ----
    {
        const uint4* src = (const uint4*)wimg;
        uint4* dst = (uint4*)s_lds;
        for (int i = t; i < W_TOT_U4; i += 256) dst[i] = src[i];
    }

    // ---- spherical harmonics for this block's 64 edges ----
    if (t < 64) {
        int e = e0 + t;
        float vx = ev[(size_t)e * 3 + 0], vy = ev[(size_t)e * 3 + 1], vz = ev[(size_t)e * 3 + 2];
        float inv = rsqrtf(vx * vx + vy * vy + vz * vz);
        float x = vx * inv, y = vy * inv, z = vz * inv;
        const float s3 = 1.7320508075688772f;
        const float s15 = 3.872983346207417f;
        const float s5 = 2.2360679774997896f;
        float4* sp = (float4*)(shb + (size_t)e * SH_PAD);
        sp[0] = make_float4(1.0f, s3 * x, s3 * y, s3 * z);
        sp[1] = make_float4(s15 * x * y, s15 * y * z, 0.5f * s5 * (3.0f * z * z - 1.0f), s15 * x * z);
        sp[2] = make_float4(0.5f * s15 * (x * x - y * y), 0.f, 0.f, 0.f);
    }

    // ---- radial A-frag (K=8, quads 1-3 zeros) ----
    bf16x8 ar = {0, 0, 0, 0, 0, 0, 0, 0};
    if (quad == 0) {
        const float4* rp = (const float4*)(rad + (size_t)(e0 + em) * 8);
        float4 u = rp[0], v = rp[1];
        ar[0] = (short)f2bf(u.x); ar[1] = (short)f2bf(u.y);
        ar[2] = (short)f2bf(u.z); ar[3] = (short)f2bf(u.w);
        ar[4] = (short)f2bf(v.x); ar[5] = (short)f2bf(v.y);
        ar[6] = (short)f2bf(v.z); ar[7] = (short)f2bf(v.w);
    }
    __syncthreads();   // the only block-wide barrier

    // ---- layer 1: [8]->[64], scale 1/sqrt(8), silu ----
#pragma unroll
    for (int nt = 0; nt < 4; ++nt) {
        bf16x8 bw = {0, 0, 0, 0, 0, 0, 0, 0};
        if (quad == 0) bw = *(const bf16x8*)(s_lds + W1_OFF + (nt * 16 + lrow) * 8);
        f32x4 cc = {0.f, 0.f, 0.f, 0.f};
        cc = MFMA16(ar, bw, cc);
#pragma unroll
        for (int r = 0; r < 4; ++r)
            act[(crow0 + r) * ACT_STRIDE + nt * 16 + lrow] =
                (unsigned short)f2bf(silu(cc[r] * 0.3535533905932738f));
    }

    // ---- layer 2: [64]->[64], scale 1/8, silu (in-place, per-wave rows) ----
    {
        bf16x8 a0 = *(const bf16x8*)(act + em * ACT_STRIDE + quad * 8);
        bf16x8 a1 = *(const bf16x8*)(act + em * ACT_STRIDE + 32 + quad * 8);
#pragma unroll
        for (int nt = 0; nt < 4; ++nt) {
            const unsigned short* wr = s_lds + W2_OFF + (nt * 16 + lrow) * 72 + quad * 8;
            bf16x8 b0 = *(const bf16x8*)wr;
            bf16x8 b1 = *(const bf16x8*)(wr + 32);
            f32x4 cc = {0.f, 0.f, 0.f, 0.f};
            cc = MFMA16(a0, b0, cc);
            cc = MFMA16(a1, b1, cc);
#pragma unroll
            for (int r = 0; r < 4; ++r)
                act[(crow0 + r) * ACT_STRIDE + nt * 16 + lrow] =
                    (unsigned short)f2bf(silu(cc[r] * 0.125f));
        }
    }

    // ---- layer 3: same shape, weights at W3_OFF ----
    {
        bf16x8 a0 = *(const bf16x8*)(act + em * ACT_STRIDE + quad * 8);
        bf16x8 a1 = *(const bf16x8*)(act + em * ACT_STRIDE + 32 + quad * 8);
#pragma unroll
        for (int nt = 0; nt < 4; ++nt) {
            const unsigned short* wr = s_lds + W3_OFF + (nt * 16 + lrow) * 72 + quad * 8;
            bf16x8 b0 = *(const bf16x8*)wr;
            bf16x8 b1 = *(const bf16x8*)(wr + 32);
            f32x4 cc = {0.f, 0.f, 0.f, 0.f};
            cc = MFMA16(a0, b0, cc);
            cc = MFMA16(a1, b1, cc);
#pragma unroll
            for (int r = 0; r < 4; ++r)
                act[(crow0 + r) * ACT_STRIDE + nt * 16 + lrow] =
                    (unsigned short)f2bf(silu(cc[r] * 0.125f));
        }
    }

    // ---- layer 4: [64]->[192] in 3 column-thirds; act region reused as stage;
    //      per-wave copyout (waves own their 16 rows) -> no barriers ----
    {
        bf16x8 a0 = *(const bf16x8*)(act + em * ACT_STRIDE + quad * 8);
        bf16x8 a1 = *(const bf16x8*)(act + em * ACT_STRIDE + 32 + quad * 8);
#pragma unroll
        for (int T = 0; T < 3; ++T) {
#pragma unroll
            for (int ntl = 0; ntl < 4; ++ntl) {
                int nt = T * 4 + ntl;
                const unsigned short* wr = s_lds + W4_OFF + (nt * 16 + lrow) * 72 + quad * 8;
                bf16x8 b0 = *(const bf16x8*)wr;
                bf16x8 b1 = *(const bf16x8*)(wr + 32);
                f32x4 cc = {0.f, 0.f, 0.f, 0.f};
                cc = MFMA16(a0, b0, cc);
                cc = MFMA16(a1, b1, cc);
#pragma unroll
                for (int r = 0; r < 4; ++r)
                    act[(crow0 + r) * ACT_STRIDE + ntl * 16 + lrow] =
                        (unsigned short)f2bf(cc[r] * 0.125f);
            }
            // copy this wave's 16 rows x 64 cols -> mix[:, T*64 : T*64+64]
#pragma unroll
            for (int i = lane; i < 128; i += 64) {
                int row = i >> 3, c16 = i & 7;
                uint4 v = *(const uint4*)(act + (wv * 16 + row) * ACT_STRIDE + c16 * 8);
                *(uint4*)(mix + (size_t)(e0 + wv * 16 + row) * MIXW + T * 64 + c16 * 8) = v;
            }
        }
    }
}

// ---------- K3a: receiver histogram ----------
__global__ __launch_bounds__(256) void k_hist(const int* __restrict__ recv,
                                              int* __restrict__ counts) {
    int e = blockIdx.x * 256 + threadIdx.x;
    atomicAdd(&counts[recv[e]], 1);
}

// ---------- K3b: single-block exclusive scan over counts ----------
__global__ __launch_bounds__(1024) void k_scan(const int* __restrict__ counts,
                                               int* __restrict__ offsets,
                                               int* __restrict__ cursor) {
    __shared__ int part[1024];
    int t = threadIdx.x;
    const int CHUNK = 10;  // 1024*10 >= 10000
    int base = t * CHUNK;
    int s = 0;
    for (int i = 0; i < CHUNK; ++i) {
        int idx = base + i;
        if (idx < N_NODES) s += counts[idx];
    }
    part[t] = s;
    __syncthreads();
    for (int off = 1; off < 1024; off <<= 1) {
        int v = 0;
        if (t >= off) v = part[t - off];
        __syncthreads();
        part[t] += v;
        __syncthreads();
    }
    int run = part[t] - s;  // exclusive base for this chunk
    for (int i = 0; i < CHUNK; ++i) {
        int idx = base + i;
        if (idx < N_NODES) {
            offsets[idx] = run;
            cursor[idx] = run;
            run += counts[idx];
        }
    }
    if (t == 1023) offsets[N_NODES] = part[1023];
}

// ---------- K3c: scatter edge ids into CSR order ----------
__global__ __launch_bounds__(256) void k_scatter(const int* __restrict__ recv,
                                                 int* __restrict__ cursor,
                                                 int* __restrict__ eids) {
    int e = blockIdx.x * 256 + threadIdx.x;
    int pos = atomicAdd(&cursor[recv[e]], 1);
    eids[pos] = e;
}

// ---------- K4: per-node aggregation + fused linear_down ----------
// One wave per node, lane = channel during agg, lane = out-channel during down.
__global__ __launch_bounds__(256) void k_aggdown(const int* __restrict__ offsets,
                                                 const int* __restrict__ eids,
                                                 const int* __restrict__ senders,
                                                 const float* __restrict__ h,
                                                 const float* __restrict__ shb,
                                                 const unsigned short* __restrict__ mix,
                                                 const float* __restrict__ Wd,
                                                 float* __restrict__ out) {
    __shared__ float sg[4][576];
    int wv = threadIdx.x >> 6;
    int lane = threadIdx.x & 63;
    int node = __builtin_amdgcn_readfirstlane(blockIdx.x * 4 + wv);
    int s0 = __builtin_amdgcn_readfirstlane(offsets[node]);
    int s1 = __builtin_amdgcn_readfirstlane(offsets[node + 1]);
    float acc[9] = {0.f, 0.f, 0.f, 0.f, 0.f, 0.f, 0.f, 0.f, 0.f};
    for (int i = s0; i < s1; ++i) {
        int eid = __builtin_amdgcn_readfirstlane(eids[i]);
        int s = __builtin_amdgcn_readfirstlane(senders[eid]);
        float hv = h[(size_t)s * CH + lane];
        const unsigned short* mrow = mix + (size_t)eid * MIXW;
        float w0 = bf2f(mrow[lane]);
        float w1 = bf2f(mrow[64 + lane]);
        float w2 = bf2f(mrow[128 + lane]);
        const float* shp = shb + (size_t)eid * SH_PAD;
        float h0 = hv * w0, h1 = hv * w1, h2 = hv * w2;
        acc[0] += h0 * shp[0];
        acc[1] += h1 * shp[1];
        acc[2] += h1 * shp[2];
        acc[3] += h1 * shp[3];
        acc[4] += h2 * shp[4];
        acc[5] += h2 * shp[5];
        acc[6] += h2 * shp[6];
        acc[7] += h2 * shp[7];
        acc[8] += h2 * shp[8];
    }
    // stash this node's agg tile in LDS (per-wave region; in-order DS => no barrier)
    float* arow = sg[wv];
#pragma unroll
    for (int m = 0; m < 9; ++m) arow[lane * 9 + m] = acc[m] * (1.0f / 32.0f);

    // linear_down: lane = output channel d; arow reads are wave-uniform (broadcast)
    float* orow = out + (size_t)node * 576;
    {
        float a = 0.f;
#pragma unroll
        for (int c = 0; c < 64; ++c) a += arow[c * 9] * Wd[c * 64 + lane];
        orow[lane] = a * 0.125f;
    }
    {
        float m3[3] = {0.f, 0.f, 0.f};
#pragma unroll
        for (int c = 0; c < 64; ++c) {
            float w = Wd[(64 + c) * 64 + lane];
#pragma unroll
            for (int mm = 0; mm < 3; ++mm) m3[mm] += arow[c * 9 + 1 + mm] * w;
        }
#pragma unroll
        for (int mm = 0; mm < 3; ++mm) orow[64 + lane * 3 + mm] = m3[mm] * 0.125f;
    }
    {
        float m5[5] = {0.f, 0.f, 0.f, 0.f, 0.f};
#pragma unroll
        for (int c = 0; c < 64; ++c) {
            float w = Wd[(128 + c) * 64 + lane];
#pragma unroll
            for (int mm = 0; mm < 5; ++mm) m5[mm] += arow[c * 9 + 4 + mm] * w;
        }
#pragma unroll
        for (int mm = 0; mm < 5; ++mm) orow[256 + lane * 5 + mm] = m5[mm] * 0.125f;
    }
}

// ---------- launcher ----------
static inline size_t align256(size_t x) { return (x + 255) & ~(size_t)255; }

extern "C" void kernel_launch(void* const* d_in, const int* in_sizes, int n_in,
                              void* d_out, int out_size, void* d_ws, size_t ws_size,
                              hipStream_t stream) {
    const float* edge_vectors = (const float*)d_in[0];
    const float* node_feats   = (const float*)d_in[1];
    const float* radial       = (const float*)d_in[2];
    const int*   senders      = (const int*)d_in[3];
    const int*   receivers    = (const int*)d_in[4];
    const float* W_up         = (const float*)d_in[5];
    const float* W_mlp1       = (const float*)d_in[6];
    const float* W_mlp2       = (const float*)d_in[7];
    const float* W_mlp3       = (const float*)d_in[8];
    const float* W_mlp4       = (const float*)d_in[9];
    const float* W_down       = (const float*)d_in[10];
    float* out = (float*)d_out;

    char* base = (char*)d_ws;
    size_t off = 0;
    float* h = (float*)(base + off);              off = align256(off + (size_t)N_NODES * CH * 4);
    float* shb = (float*)(base + off);            off = align256(off + (size_t)N_EDGES * SH_PAD * 4);
    unsigned short* mix = (unsigned short*)(base + off); off = align256(off + (size_t)N_EDGES * MIXW * 2);
    unsigned short* wimg = (unsigned short*)(base + off); off = align256(off + (size_t)W_TOT * 2);
    int* counts = (int*)(base + off);             off = align256(off + (size_t)N_NODES * 4);
    int* offsets = (int*)(base + off);            off = align256(off + (size_t)(N_NODES + 1) * 4);
    int* cursor = (int*)(base + off);             off = align256(off + (size_t)N_NODES * 4);
    int* eids = (int*)(base + off);               off = align256(off + (size_t)N_EDGES * 4);

    hipMemsetAsync(counts, 0, (size_t)N_NODES * 4, stream);

    k_prep<<<(W_TOT + 255) / 256, 256, 0, stream>>>(W_mlp1, W_mlp2, W_mlp3, W_mlp4, wimg);
    k_h<<<N_NODES / 4, 256, 0, stream>>>(node_feats, W_up, h);
    k_mlp<<<N_EDGES / 64, 256, 0, stream>>>(edge_vectors, radial, wimg, shb, mix);
    k_hist<<<N_EDGES / 256, 256, 0, stream>>>(receivers, counts);
    k_scan<<<1, 1024, 0, stream>>>(counts, offsets, cursor);
    k_scatter<<<N_EDGES / 256, 256, 0, stream>>>(receivers, cursor, eids);
    k_aggdown<<<N_NODES / 4, 256, 0, stream>>>(offsets, eids, senders, h, shb, mix,
                                               W_down, out);
}

// Round 6
// 260.225 us; speedup vs baseline: 14.9201x; 1.1640x over previous
//
#include <hip/hip_runtime.h>
#include <hip/hip_bf16.h>
#include <math.h>

#define N_NODES 10000
#define N_EDGES 320000
#define CH 64
#define SH_PAD 12   // sh stored padded to 12 floats/row for 16B-aligned stores
#define MIXW 192    // N_L * CH

// weight-image layout (shorts), stride-72 rows (16B-aligned row starts)
#define W1_OFF 0        // [64][8]
#define W2_OFF 512      // [64][72]
#define W3_OFF 5120     // [64][72]
#define W4_OFF 9728     // [192][72]
#define W_TOT 23552     // shorts
#define ACT_STRIDE 72

#define EPB 128         // edges per k_mlp block (256 thr = 4 waves, 32 edges/wave)

typedef __attribute__((ext_vector_type(8))) short bf16x8;
typedef __attribute__((ext_vector_type(4))) float f32x4;
#define MFMA16(a, b, c) __builtin_amdgcn_mfma_f32_16x16x32_bf16(a, b, c, 0, 0, 0)

// ---------- small helpers ----------
__device__ __forceinline__ float bf2f(unsigned short u) {
    union { unsigned int i; float f; } v; v.i = ((unsigned int)u) << 16; return v.f;
}
__device__ __forceinline__ unsigned short f2bf(float f) {
    unsigned int x = __float_as_uint(f);
    unsigned int r = x + 0x7fffu + ((x >> 16) & 1u);   // RNE
    return (unsigned short)(r >> 16);
}
__device__ __forceinline__ float silu(float t) {
    return t / (1.0f + __expf(-t));
}

// ---------- K0: one-time weight convert/transpose to bf16 image ----------
__global__ __launch_bounds__(256) void k_prep(const float* __restrict__ W1,
                                              const float* __restrict__ W2,
                                              const float* __restrict__ W3,
                                              const float* __restrict__ W4,
                                              unsigned short* __restrict__ wimg) {
    int i = blockIdx.x * 256 + threadIdx.x;
    if (i >= W_TOT) return;
    float v;
    if (i < W2_OFF) {
        int n = i >> 3, k = i & 7;
        v = W1[k * 64 + n];
    } else if (i < W3_OFF) {
        int j = i - W2_OFF; int n = j / 72, k = j % 72;
        v = (k < 64) ? W2[k * 64 + n] : 0.f;
    } else if (i < W4_OFF) {
        int j = i - W3_OFF; int n = j / 72, k = j % 72;
        v = (k < 64) ? W3[k * 64 + n] : 0.f;
    } else {
        int j = i - W4_OFF; int n = j / 72, k = j % 72;
        v = (k < 64) ? W4[k * MIXW + n] : 0.f;
    }
    wimg[i] = f2bf(v);
}

// ---------- K1: h = (node_feats @ W_up) / 8 ----------
__global__ __launch_bounds__(256) void k_h(const float* __restrict__ nf,
                                           const float* __restrict__ Wup,
                                           float* __restrict__ h) {
    int node = __builtin_amdgcn_readfirstlane(blockIdx.x * 4 + (threadIdx.x >> 6));
    int lane = threadIdx.x & 63;
    const float* nrow = nf + (size_t)node * CH;
    float acc = 0.f;
#pragma unroll
    for (int k = 0; k < CH; ++k) acc += nrow[k] * Wup[k * CH + lane];
    h[(size_t)node * CH + lane] = acc * 0.125f;
}

// ---------- K_mlp v3: SH + radial MLP; weights from global (L2), LDS = act only ----
// 256 thr = 4 waves; 128 edges/block; 32 edges/wave (two 16-row A-tiles).
// LDS: act[128][72] bf16 (18 KB) -> no LDS occupancy cap. No barriers at all:
// each wave only touches its own 32 act rows (in-order DS within a wave).
__global__ __launch_bounds__(256) void k_mlp(const float* __restrict__ ev,
                                             const float* __restrict__ rad,
                                             const unsigned short* __restrict__ wimg,
                                             float* __restrict__ shb,
                                             unsigned short* __restrict__ mix) {
    __shared__ unsigned short act[EPB * ACT_STRIDE];   // 18432 B

    const int t = threadIdx.x;
    const int e0 = blockIdx.x * EPB;
    const int wv = t >> 6;
    const int lane = t & 63;
    const int lrow = lane & 15;
    const int quad = lane >> 4;
    const int wr0 = wv * 32;                 // this wave's first act row
    const int em0 = wr0 + lrow;              // A-tile0 row
    const int em1 = em0 + 16;                // A-tile1 row
    const int cr0 = wr0 + quad * 4;          // tile0 C-row base
    const int cr1 = cr0 + 16;                // tile1 C-row base

    // ---- spherical harmonics for this block's 128 edges ----
    if (t < EPB) {
        int e = e0 + t;
        float vx = ev[(size_t)e * 3 + 0], vy = ev[(size_t)e * 3 + 1], vz = ev[(size_t)e * 3 + 2];
        float inv = rsqrtf(vx * vx + vy * vy + vz * vz);
        float x = vx * inv, y = vy * inv, z = vz * inv;
        const float s3 = 1.7320508075688772f;
        const float s15 = 3.872983346207417f;
        const float s5 = 2.2360679774997896f;
        float4* sp = (float4*)(shb + (size_t)e * SH_PAD);
        sp[0] = make_float4(1.0f, s3 * x, s3 * y, s3 * z);
        sp[1] = make_float4(s15 * x * y, s15 * y * z, 0.5f * s5 * (3.0f * z * z - 1.0f), s15 * x * z);
        sp[2] = make_float4(0.5f * s15 * (x * x - y * y), 0.f, 0.f, 0.f);
    }

    // ---- radial A-frags (K=8 lives in quad 0) ----
    bf16x8 ar0 = {0, 0, 0, 0, 0, 0, 0, 0};
    bf16x8 ar1 = {0, 0, 0, 0, 0, 0, 0, 0};
    if (quad == 0) {
        const float4* rp0 = (const float4*)(rad + (size_t)(e0 + em0) * 8);
        const float4* rp1 = (const float4*)(rad + (size_t)(e0 + em1) * 8);
        float4 u = rp0[0], v = rp0[1];
        ar0[0] = (short)f2bf(u.x); ar0[1] = (short)f2bf(u.y);
        ar0[2] = (short)f2bf(u.z); ar0[3] = (short)f2bf(u.w);
        ar0[4] = (short)f2bf(v.x); ar0[5] = (short)f2bf(v.y);
        ar0[6] = (short)f2bf(v.z); ar0[7] = (short)f2bf(v.w);
        u = rp1[0]; v = rp1[1];
        ar1[0] = (short)f2bf(u.x); ar1[1] = (short)f2bf(u.y);
        ar1[2] = (short)f2bf(u.z); ar1[3] = (short)f2bf(u.w);
        ar1[4] = (short)f2bf(v.x); ar1[5] = (short)f2bf(v.y);
        ar1[6] = (short)f2bf(v.z); ar1[7] = (short)f2bf(v.w);
    }

    // ---- layer 1: [8]->[64], scale 1/sqrt(8), silu ----
#pragma unroll
    for (int nt = 0; nt < 4; ++nt) {
        bf16x8 bw = {0, 0, 0, 0, 0, 0, 0, 0};
        if (quad == 0) bw = *(const bf16x8*)(wimg + W1_OFF + (nt * 16 + lrow) * 8);
        f32x4 c0 = {0.f, 0.f, 0.f, 0.f};
        f32x4 c1 = {0.f, 0.f, 0.f, 0.f};
        c0 = MFMA16(ar0, bw, c0);
        c1 = MFMA16(ar1, bw, c1);
#pragma unroll
        for (int r = 0; r < 4; ++r) {
            act[(cr0 + r) * ACT_STRIDE + nt * 16 + lrow] =
                (unsigned short)f2bf(silu(c0[r] * 0.3535533905932738f));
            act[(cr1 + r) * ACT_STRIDE + nt * 16 + lrow] =
                (unsigned short)f2bf(silu(c1[r] * 0.3535533905932738f));
        }
    }

    // ---- layers 2 & 3: [64]->[64], scale 1/8, silu, in-place per-wave ----
#pragma unroll
    for (int L = 0; L < 2; ++L) {
        const unsigned short* wbase = wimg + (L == 0 ? W2_OFF : W3_OFF);
        bf16x8 a00 = *(const bf16x8*)(act + em0 * ACT_STRIDE + quad * 8);
        bf16x8 a01 = *(const bf16x8*)(act + em0 * ACT_STRIDE + 32 + quad * 8);
        bf16x8 a10 = *(const bf16x8*)(act + em1 * ACT_STRIDE + quad * 8);
        bf16x8 a11 = *(const bf16x8*)(act + em1 * ACT_STRIDE + 32 + quad * 8);
        bf16x8 b[4][2];
#pragma unroll
        for (int nt = 0; nt < 4; ++nt)
#pragma unroll
            for (int kh = 0; kh < 2; ++kh)
                b[nt][kh] = *(const bf16x8*)(wbase + (nt * 16 + lrow) * 72 + kh * 32 + quad * 8);
#pragma unroll
        for (int nt = 0; nt < 4; ++nt) {
            f32x4 c0 = {0.f, 0.f, 0.f, 0.f};
            f32x4 c1 = {0.f, 0.f, 0.f, 0.f};
            c0 = MFMA16(a00, b[nt][0], c0);
            c0 = MFMA16(a01, b[nt][1], c0);
            c1 = MFMA16(a10, b[nt][0], c1);
            c1 = MFMA16(a11, b[nt][1], c1);
#pragma unroll
            for (int r = 0; r < 4; ++r) {
                act[(cr0 + r) * ACT_STRIDE + nt * 16 + lrow] =
                    (unsigned short)f2bf(silu(c0[r] * 0.125f));
                act[(cr1 + r) * ACT_STRIDE + nt * 16 + lrow] =
                    (unsigned short)f2bf(silu(c1[r] * 0.125f));
            }
        }
    }

    // ---- layer 4: [64]->[192] in 3 thirds; act reused as stage; per-wave copyout ----
    {
        // input frags MUST be loaded before the stage overwrites act
        bf16x8 a00 = *(const bf16x8*)(act + em0 * ACT_STRIDE + quad * 8);
        bf16x8 a01 = *(const bf16x8*)(act + em0 * ACT_STRIDE + 32 + quad * 8);
        bf16x8 a10 = *(const bf16x8*)(act + em1 * ACT_STRIDE + quad * 8);
        bf16x8 a11 = *(const bf16x8*)(act + em1 * ACT_STRIDE + 32 + quad * 8);
#pragma unroll
        for (int T = 0; T < 3; ++T) {
            bf16x8 b[4][2];
#pragma unroll
            for (int ntl = 0; ntl < 4; ++ntl)
#pragma unroll
                for (int kh = 0; kh < 2; ++kh)
                    b[ntl][kh] = *(const bf16x8*)(wimg + W4_OFF +
                        ((T * 4 + ntl) * 16 + lrow) * 72 + kh * 32 + quad * 8);
#pragma unroll
            for (int ntl = 0; ntl < 4; ++ntl) {
                f32x4 c0 = {0.f, 0.f, 0.f, 0.f};
                f32x4 c1 = {0.f, 0.f, 0.f, 0.f};
                c0 = MFMA16(a00, b[ntl][0], c0);
                c0 = MFMA16(a01, b[ntl][1], c0);
                c1 = MFMA16(a10, b[ntl][0], c1);
                c1 = MFMA16(a11, b[ntl][1], c1);
#pragma unroll
                for (int r = 0; r < 4; ++r) {
                    act[(cr0 + r) * ACT_STRIDE + ntl * 16 + lrow] =
                        (unsigned short)f2bf(c0[r] * 0.125f);
                    act[(cr1 + r) * ACT_STRIDE + ntl * 16 + lrow] =
                        (unsigned short)f2bf(c1[r] * 0.125f);
                }
            }
            // copy wave's 32 rows x 64 cols -> mix[:, T*64 .. T*64+64)
#pragma unroll
            for (int j = 0; j < 4; ++j) {
                int idx = lane + 64 * j;          // 0..255
                int row = idx >> 3, c8 = idx & 7;
                uint4 v = *(const uint4*)(act + (wr0 + row) * ACT_STRIDE + c8 * 8);
                *(uint4*)(mix + (size_t)(e0 + wr0 + row) * MIXW + T * 64 + c8 * 8) = v;
            }
        }
    }
}

// ---------- K3a: receiver histogram ----------
__global__ __launch_bounds__(256) void k_hist(const int* __restrict__ recv,
                                              int* __restrict__ counts) {
    int e = blockIdx.x * 256 + threadIdx.x;
    atomicAdd(&counts[recv[e]], 1);
}

// ---------- K3b: single-block exclusive scan over counts ----------
__global__ __launch_bounds__(1024) void k_scan(const int* __restrict__ counts,
                                               int* __restrict__ offsets,
                                               int* __restrict__ cursor) {
    __shared__ int part[1024];
    int t = threadIdx.x;
    const int CHUNK = 10;  // 1024*10 >= 10000
    int base = t * CHUNK;
    int s = 0;
    for (int i = 0; i < CHUNK; ++i) {
        int idx = base + i;
        if (idx < N_NODES) s += counts[idx];
    }
    part[t] = s;
    __syncthreads();
    for (int off = 1; off < 1024; off <<= 1) {
        int v = 0;
        if (t >= off) v = part[t - off];
        __syncthreads();
        part[t] += v;
        __syncthreads();
    }
    int run = part[t] - s;  // exclusive base for this chunk
    for (int i = 0; i < CHUNK; ++i) {
        int idx = base + i;
        if (idx < N_NODES) {
            offsets[idx] = run;
            cursor[idx] = run;
            run += counts[idx];
        }
    }
    if (t == 1023) offsets[N_NODES] = part[1023];
}

// ---------- K3c: scatter edge ids into CSR order ----------
__global__ __launch_bounds__(256) void k_scatter(const int* __restrict__ recv,
                                                 int* __restrict__ cursor,
                                                 int* __restrict__ eids) {
    int e = blockIdx.x * 256 + threadIdx.x;
    int pos = atomicAdd(&cursor[recv[e]], 1);
    eids[pos] = e;
}

// ---------- K4: per-node aggregation + fused linear_down ----------
// One wave per node. Index fetch is batched (64 lanes load 64 edges' eid/sender
// in parallel), then broadcast by __shfl -> no per-edge dependent load chain.
__global__ __launch_bounds__(256) void k_aggdown(const int* __restrict__ offsets,
                                                 const int* __restrict__ eids,
                                                 const int* __restrict__ senders,
                                                 const float* __restrict__ h,
                                                 const float* __restrict__ shb,
                                                 const unsigned short* __restrict__ mix,
                                                 const float* __restrict__ Wd,
                                                 float* __restrict__ out) {
    __shared__ float sg[4][576];
    int wv = threadIdx.x >> 6;
    int lane = threadIdx.x & 63;
    int node = __builtin_amdgcn_readfirstlane(blockIdx.x * 4 + wv);
    int s0 = __builtin_amdgcn_readfirstlane(offsets[node]);
    int s1 = __builtin_amdgcn_readfirstlane(offsets[node + 1]);
    int cnt = s1 - s0;
    float acc[9] = {0.f, 0.f, 0.f, 0.f, 0.f, 0.f, 0.f, 0.f, 0.f};
    for (int base = 0; base < cnt; base += 64) {
        int n = cnt - base; if (n > 64) n = 64;
        int eidv = 0, sndv = 0;
        if (lane < n) {
            eidv = eids[s0 + base + lane];
            sndv = senders[eidv];
        }
        for (int i = 0; i < n; ++i) {
            int eid = __builtin_amdgcn_readfirstlane(__shfl(eidv, i));
            int s   = __builtin_amdgcn_readfirstlane(__shfl(sndv, i));
            float hv = h[(size_t)s * CH + lane];
            const unsigned short* mrow = mix + (size_t)eid * MIXW;
            float w0 = bf2f(mrow[lane]);
            float w1 = bf2f(mrow[64 + lane]);
            float w2 = bf2f(mrow[128 + lane]);
            const float* shp = shb + (size_t)eid * SH_PAD;
            float h0 = hv * w0, h1 = hv * w1, h2 = hv * w2;
            acc[0] += h0 * shp[0];
            acc[1] += h1 * shp[1];
            acc[2] += h1 * shp[2];
            acc[3] += h1 * shp[3];
            acc[4] += h2 * shp[4];
            acc[5] += h2 * shp[5];
            acc[6] += h2 * shp[6];
            acc[7] += h2 * shp[7];
            acc[8] += h2 * shp[8];
        }
    }
    // stash node's agg tile in LDS (per-wave region; in-order DS => no barrier)
    float* arow = sg[wv];
#pragma unroll
    for (int m = 0; m < 9; ++m) arow[lane * 9 + m] = acc[m] * (1.0f / 32.0f);

    // linear_down: lane = output channel d; arow reads broadcast
    float* orow = out + (size_t)node * 576;
    {
        float a = 0.f;
#pragma unroll
        for (int c = 0; c < 64; ++c) a += arow[c * 9] * Wd[c * 64 + lane];
        orow[lane] = a * 0.125f;
    }
    {
        float m3[3] = {0.f, 0.f, 0.f};
#pragma unroll
        for (int c = 0; c < 64; ++c) {
            float w = Wd[(64 + c) * 64 + lane];
#pragma unroll
            for (int mm = 0; mm < 3; ++mm) m3[mm] += arow[c * 9 + 1 + mm] * w;
        }
#pragma unroll
        for (int mm = 0; mm < 3; ++mm) orow[64 + lane * 3 + mm] = m3[mm] * 0.125f;
    }
    {
        float m5[5] = {0.f, 0.f, 0.f, 0.f, 0.f};
#pragma unroll
        for (int c = 0; c < 64; ++c) {
            float w = Wd[(128 + c) * 64 + lane];
#pragma unroll
            for (int mm = 0; mm < 5; ++mm) m5[mm] += arow[c * 9 + 4 + mm] * w;
        }
#pragma unroll
        for (int mm = 0; mm < 5; ++mm) orow[256 + lane * 5 + mm] = m5[mm] * 0.125f;
    }
}

// ---------- launcher ----------
static inline size_t align256(size_t x) { return (x + 255) & ~(size_t)255; }

extern "C" void kernel_launch(void* const* d_in, const int* in_sizes, int n_in,
                              void* d_out, int out_size, void* d_ws, size_t ws_size,
                              hipStream_t stream) {
    const float* edge_vectors = (const float*)d_in[0];
    const float* node_feats   = (const float*)d_in[1];
    const float* radial       = (const float*)d_in[2];
    const int*   senders      = (const int*)d_in[3];
    const int*   receivers    = (const int*)d_in[4];
    const float* W_up         = (const float*)d_in[5];
    const float* W_mlp1       = (const float*)d_in[6];
    const float* W_mlp2       = (const float*)d_in[7];
    const float* W_mlp3       = (const float*)d_in[8];
    const float* W_mlp4       = (const float*)d_in[9];
    const float* W_down       = (const float*)d_in[10];
    float* out = (float*)d_out;

    char* base = (char*)d_ws;
    size_t off = 0;
    float* h = (float*)(base + off);              off = align256(off + (size_t)N_NODES * CH * 4);
    float* shb = (float*)(base + off);            off = align256(off + (size_t)N_EDGES * SH_PAD * 4);
    unsigned short* mix = (unsigned short*)(base + off); off = align256(off + (size_t)N_EDGES * MIXW * 2);
    unsigned short* wimg = (unsigned short*)(base + off); off = align256(off + (size_t)W_TOT * 2);
    int* counts = (int*)(base + off);             off = align256(off + (size_t)N_NODES * 4);
    int* offsets = (int*)(base + off);            off = align256(off + (size_t)(N_NODES + 1) * 4);
    int* cursor = (int*)(base + off);             off = align256(off + (size_t)N_NODES * 4);
    int* eids = (int*)(base + off);               off = align256(off + (size_t)N_EDGES * 4);

    hipMemsetAsync(counts, 0, (size_t)N_NODES * 4, stream);

    k_prep<<<(W_TOT + 255) / 256, 256, 0, stream>>>(W_mlp1, W_mlp2, W_mlp3, W_mlp4, wimg);
    k_h<<<N_NODES / 4, 256, 0, stream>>>(node_feats, W_up, h);
    k_mlp<<<N_EDGES / EPB, 256, 0, stream>>>(edge_vectors, radial, wimg, shb, mix);
    k_hist<<<N_EDGES / 256, 256, 0, stream>>>(receivers, counts);
    k_scan<<<1, 1024, 0, stream>>>(counts, offsets, cursor);
    k_scatter<<<N_EDGES / 256, 256, 0, stream>>>(receivers, cursor, eids);
    k_aggdown<<<N_NODES / 4, 256, 0, stream>>>(offsets, eids, senders, h, shb, mix,
                                               W_down, out);
}